// Round 5
// baseline (117.980 us; speedup 1.0000x reference)
//
#include <hip/hip_runtime.h>

// SoftRAM attention: S=128, B=256 bits, H=16 heads, NB=12 bits/neuron, PB=7.
// addr(i,j,h,n) = aq_i | ak_j | ap_{i-j}, disjoint bit groups per (h,n).
//
// R13: split stream from logic. R10 (TLP) and R12 (async pipeline) were both
// null; R11 (work removal) won -> softram's ~32us is the 64MB memory stream
// running at ~2.6 B/cyc/CU inside a barrier-structured, LDS-heavy kernel
// (same chip streams 268MB @6.5TB/s in the harness fills).
//  - prep_kernel: one wave per (h,n) row, streams the 16KB row (4-deep load
//    ring), packs signs into its own LDS sigma byte-table, and (VALU is idle
//    under the stream) absorbs the repack: fast rows emit the 512B
//    lane-distributed Wfull bit-LUT (2MB total), fallback rows emit the 4KB
//    sigma byte-table to global (<=16MB). Token pack rides along as 8 extra
//    blocks (one launch saved).
//  - softram_kernel: pure logic. Fast waves: load 8B/lane Wfull + class
//    build + lane-parallel prefix-XOR sweep (no byte table, no repack, no
//    float staging). Fallback waves: global_load_lds the 4KB byte-table +
//    verbatim masked sweep. All inner loops byte-identical to R11/R12
//    (verified absmax 0), only relocated.

#define S 128
#define B 256
#define H 16
#define NB 12

__device__ __forceinline__ unsigned sig(unsigned x) {
    return x ^ ((x >> 3) & 0x70u) ^ ((x >> 6) & 0x70u);
}

// token bit c lives at packed word TW(c), bit TP(c)
#define TW(c) ((((c) & 3) << 1) + ((c) >> 7))
#define TP(c) (((c) >> 2) & 31)

// ---------------------------------------------------------------- prep ----
__global__ __launch_bounds__(256, 4) void prep_kernel(
    const int* __restrict__ tokens,        // [S,B] 0/1
    const float* __restrict__ memory,      // [H,B,4096]
    const int* __restrict__ connections,   // [H,B,NB]
    unsigned* __restrict__ tokP,           // [8][S] packed tokens
    unsigned long long* __restrict__ psW,  // [4096][64] fast-row bit-LUT
    unsigned char* __restrict__ psB)       // [4096][4096] fb-row byte table
{
    const int wid  = threadIdx.x >> 6;
    const int lane = threadIdx.x & 63;

    if (blockIdx.x >= 1024) {
        // ---- token pack (8 blocks): coalesced row loads + ballots ----
        const int bid2 = blockIdx.x - 1024;
        const int4* tp = (const int4*)tokens;
        #pragma unroll
        for (int rr = 0; rr < 4; ++rr) {
            int i = bid2 * 16 + wid * 4 + rr;
            int4 x = tp[i * 64 + lane];
            unsigned long long B0 = __ballot((x.x & 1) != 0);
            unsigned long long B1 = __ballot((x.y & 1) != 0);
            unsigned long long B2 = __ballot((x.z & 1) != 0);
            unsigned long long B3 = __ballot((x.w & 1) != 0);
            int c = lane >> 1;
            unsigned long long s01 = (c & 1) ? B1 : B0;
            unsigned long long s23 = (c & 1) ? B3 : B2;
            unsigned long long s   = (c & 2) ? s23 : s01;
            unsigned word = (lane & 1) ? (unsigned)(s >> 32) : (unsigned)s;
            if (lane < 8) tokP[lane * 128 + i] = word;
        }
        return;
    }

    __shared__ __align__(16) unsigned char bytetab[4][4096];  // 16 KB
    const int r = blockIdx.x * 4 + wid;    // row = h*256+n
    unsigned char* __restrict__ bt = bytetab[wid];

    // ---- masks from connections (wave-uniform via shfl) ----
    int c_l = (lane < NB) ? connections[(size_t)r * NB + lane] : 0;
    unsigned qmask = 0, kmask = 0, pmask = 0;
    #pragma unroll
    for (int b = 0; b < NB; ++b) {
        int cb = __shfl(c_l, b);
        qmask |= (unsigned)(cb < 256) << b;
        kmask |= (unsigned)(cb >= 256 && cb < 512) << b;
        pmask |= (unsigned)(cb >= 512) << b;
    }
    const int qb = __popc(qmask);
    const int kb = __popc(kmask);
    const bool fast = (pmask == 0);

    // ---- stream the 16KB row, 4-deep ring; pack signs into LDS table;
    //      fallback rows also mirror the dwords to global ----
    const float4* mp = (const float4*)(memory + ((size_t)r << 12));
    unsigned char* __restrict__ gb = psB + ((size_t)r << 12);
    float4 va[4];
    #pragma unroll
    for (int t = 0; t < 4; ++t) va[t] = mp[lane + 64 * t];
    #pragma unroll
    for (int t = 0; t < 16; ++t) {
        float4 v = va[t & 3];
        if (t + 4 < 16) va[t & 3] = mp[lane + 64 * (t + 4)];
        unsigned w = (unsigned)(v.x > 0.f)
                   | ((unsigned)(v.y > 0.f) << 8)
                   | ((unsigned)(v.z > 0.f) << 16)
                   | ((unsigned)(v.w > 0.f) << 24);
        unsigned sp = sig(4u * (unsigned)(lane + 64 * t));
        *(unsigned*)&bt[sp] = w;           // sigma keeps bits 0-3 -> aligned
        if (!fast) *(unsigned*)&gb[sp] = w;
    }

    if (!fast) return;

    // ---- repack to lane-distributed bit-LUT: lane w holds global bits
    //      gbit in [64w, 64w+64), gbit = (Lcls << SBITS) | Scls ----
    const bool formA = (qb <= 6);
    const int SBITS  = formA ? qb : kb;
    unsigned apl = 0, aul = 0;
    {
        int scnt = 0, lcnt = 0;
        #pragma unroll
        for (int b = 0; b < NB; ++b) {
            int cb = __shfl(c_l, b);
            bool isS = formA ? (cb < 256) : (cb >= 256);
            if (isS) {
                apl |= (((unsigned)lane >> scnt) & 1u) << b;
                ++scnt;
            } else {
                int p = SBITS + lcnt;
                if (p < 6) apl |= (((unsigned)lane >> p) & 1u) << b;
                else       aul |= (((unsigned)lane >> (p - 6)) & 1u) << b;
                ++lcnt;
            }
        }
    }
    const unsigned spl  = sig(apl);
    const unsigned saul = sig(aul);
    unsigned Wlo = 0, Whi = 0;
    #pragma unroll 8
    for (int it = 0; it < 64; ++it) {
        unsigned sau  = (unsigned)__builtin_amdgcn_readlane((int)saul, it);
        unsigned bitv = bt[sau ^ spl] & 1u;       // sign at gbit = it*64+lane
        unsigned long long Bm = __ballot(bitv != 0u);
#if __has_builtin(__builtin_amdgcn_writelane)
        Wlo = (unsigned)__builtin_amdgcn_writelane((int)(unsigned)Bm, it, (int)Wlo);
        Whi = (unsigned)__builtin_amdgcn_writelane((int)(unsigned)(Bm >> 32), it, (int)Whi);
#else
        Wlo = (lane == it) ? (unsigned)Bm : Wlo;
        Whi = (lane == it) ? (unsigned)(Bm >> 32) : Whi;
#endif
    }
    psW[(size_t)r * 64 + lane] = ((unsigned long long)Whi << 32) | Wlo;
}

// ------------------------------------------------------------- softram ----
__global__ __launch_bounds__(256, 4) void softram_kernel(
    const unsigned* __restrict__ tokP,     // [8][S] packed tokens
    const int* __restrict__ connections,   // [H,B,NB]
    const unsigned long long* __restrict__ psW,
    const unsigned char* __restrict__ psB,
    unsigned char* __restrict__ pc)        // [4][256][128] per-group counts
{
    const int bid  = blockIdx.x;
    const int g    = bid >> 8;             // head group (0..3)
    const int n    = bid & 255;            // neuron
    const int tid  = threadIdx.x;
    const int wid  = tid >> 6;             // wave in block (0..3)
    const int hg   = g * 4 + wid;          // global head
    const int r    = hg * 256 + n;         // row
    const int lane = tid & 63;

    __shared__ __align__(16) unsigned char  bytetab[4][4096];  // 16 KB (fb)
    __shared__ __align__(16) unsigned int   tokT[8 * S];       // 4 KB packed
    __shared__ __align__(16) unsigned short akT[4][S];
    __shared__ __align__(16) unsigned short apt[4][S];
    __shared__ int            conns[4][NB];
    __shared__ unsigned int   parts[4][4];

    unsigned char* __restrict__ bt = bytetab[wid];

    // ---- stage packed tokens (4KB, coalesced, L2-hot) + conns ----
    ((int4*)tokT)[tid] = ((const int4*)tokP)[tid];
    if (tid < 4 * NB) {
        int hh = tid / NB, b = tid - hh * NB;
        conns[hh][b] = connections[(size_t)(g * 4 + hh) * (B * NB) + n * NB + b];
    }
    __syncthreads();   // barrier #1 (drains all VMEM -> vmcnt==0 here)

    // ---- per-head masks (wave-uniform) ----
    unsigned qmask = 0, kmask = 0, pmask = 0;
    #pragma unroll
    for (int b = 0; b < NB; ++b) {
        int c = conns[wid][b];
        qmask |= (unsigned)(c < 256) << b;
        kmask |= (unsigned)(c >= 256 && c < 512) << b;
        pmask |= (unsigned)(c >= 512) << b;
    }
    const int qb = __popc(qmask);
    const int kb = __popc(kmask);
    const bool fast = (pmask == 0);

    unsigned long long rlo = 0, rhi = 0;

    if (fast) {
        // ---- fast path: load lane's Wfull word, class build, prefix sweep
        const unsigned long long Wfull = psW[(size_t)r * 64 + lane];

        unsigned qclsA = 0, qclsB = 0;
        #pragma unroll
        for (int e = 0; e < 2; ++e) {
            int ii = lane + 64 * e;
            unsigned qc = 0, kc = 0;
            int qn = 0, kn = 0;
            #pragma unroll
            for (int b = 0; b < NB; ++b) {
                int c = conns[wid][b];     // wave-uniform -> uniform branches
                if (c < 256) {
                    qc |= ((tokT[TW(c) * S + ii] >> TP(c)) & 1u) << qn;
                    ++qn;
                } else {
                    int c2 = c - 256;
                    kc |= ((tokT[TW(c2) * S + ii] >> TP(c2)) & 1u) << kn;
                    ++kn;
                }
            }
            akT[wid][ii] = (unsigned short)kc;
            if (e == 0) qclsA = qc; else qclsB = qc;
        }

        if (qb <= 6) {   // formA
            // lane-parallel prefix-XOR over keys. lane j = key j (half 1),
            // key 64+j (half 2). V_j = LUTword(kcls_j) >> (g0_j & 63);
            // prefix_j = XOR_{j'<=j} V_j'; r_i (i=j) = bit qcls_i of prefix_j.
            unsigned kclsA = akT[wid][lane];
            unsigned g0 = kclsA << qb;
            unsigned long long V = __shfl(Wfull, (int)(g0 >> 6)) >> (g0 & 63u);
            #pragma unroll
            for (int d = 1; d < 64; d <<= 1) {
                unsigned long long u = __shfl_up(V, (unsigned)d);
                V ^= (lane >= d) ? u : 0ull;
            }
            rlo = __ballot(((V >> qclsA) & 1ull) != 0ull);
            const unsigned long long Abase = __shfl(V, 63);

            unsigned kclsB = akT[wid][64 + lane];
            unsigned g1 = kclsB << qb;
            unsigned long long V1 = __shfl(Wfull, (int)(g1 >> 6)) >> (g1 & 63u);
            #pragma unroll
            for (int d = 1; d < 64; d <<= 1) {
                unsigned long long u = __shfl_up(V1, (unsigned)d);
                V1 ^= (lane >= d) ? u : 0ull;
            }
            V1 ^= Abase;
            rhi = __ballot(((V1 >> qclsB) & 1ull) != 0ull);
        } else {
            // kb <= 5: prefix-XOR of one-hot key classes (32-bit), then
            // r_i = parity(LUTrow[qcls_i] & prefix_i).
            unsigned kclsA = akT[wid][lane];
            unsigned C = 1u << kclsA;
            #pragma unroll
            for (int d = 1; d < 64; d <<= 1) {
                unsigned u = __shfl_up(C, (unsigned)d);
                C ^= (lane >= d) ? u : 0u;
            }
            unsigned g0a = qclsA << kb;
            unsigned W0 = (unsigned)(__shfl(Wfull, (int)(g0a >> 6)) >> (g0a & 63u));
            rlo = __ballot((__popc(W0 & C) & 1) != 0);
            const unsigned Cbase = __shfl(C, 63);

            unsigned kclsB = akT[wid][64 + lane];
            unsigned C1 = 1u << kclsB;
            #pragma unroll
            for (int d = 1; d < 64; d <<= 1) {
                unsigned u = __shfl_up(C1, (unsigned)d);
                C1 ^= (lane >= d) ? u : 0u;
            }
            C1 ^= Cbase;
            unsigned g0b = qclsB << kb;
            unsigned W1 = (unsigned)(__shfl(Wfull, (int)(g0b >> 6)) >> (g0b & 63u));
            rhi = __ballot((__popc(W1 & C1) & 1) != 0);
        }
    } else {
        // ---- P fallback: pull the 4KB byte table, lanes = queries ----
        const unsigned char* __restrict__ gb = psB + ((size_t)r << 12);
#if __has_builtin(__builtin_amdgcn_global_load_lds)
        #pragma unroll
        for (int t = 0; t < 4; ++t)
            __builtin_amdgcn_global_load_lds(
                (const __attribute__((address_space(1))) void*)(gb + t * 1024 + lane * 16),
                (__attribute__((address_space(3))) void*)(bt + t * 1024 + lane * 16),
                16, 0, 0);
#else
        #pragma unroll
        for (int t = 0; t < 4; ++t)
            *(float4*)(bt + t * 1024 + lane * 16) =
                *(const float4*)(gb + t * 1024 + lane * 16);
#endif

        unsigned aqv0 = 0, aqv1 = 0;
        #pragma unroll
        for (int e = 0; e < 2; ++e) {
            int ii = lane + 64 * e;
            unsigned aq = 0, ak = 0, ap = 0;
            #pragma unroll
            for (int b = 0; b < NB; ++b) {
                int c = conns[wid][b];
                if (c < 256) {
                    aq |= ((tokT[TW(c) * S + ii] >> TP(c)) & 1u) << b;
                } else if (c < 512) {
                    int c2 = c - 256;
                    ak |= ((tokT[TW(c2) * S + ii] >> TP(c2)) & 1u) << b;
                } else {
                    ap |= (((unsigned)ii >> (c - 512)) & 1u) << b;
                }
            }
            akT[wid][ii] = (unsigned short)sig(ak);
            apt[wid][ii] = (unsigned short)sig(ap);
            if (e == 0) aqv0 = sig(aq); else aqv1 = sig(aq);
        }

        asm volatile("s_waitcnt vmcnt(0)" ::: "memory");
        __builtin_amdgcn_sched_barrier(0);

        // queries i=lane (acc0) and i=lane+64 (acc1); arithmetic causal masks.
        unsigned acc0 = 0, acc1 = 0;
        for (int s8 = 0; s8 < 8; ++s8) {       // j = 0..63
            uint4 uk = *(const uint4*)&akT[wid][s8 * 8];
            #pragma unroll
            for (int t = 0; t < 8; ++t) {
                int j = s8 * 8 + t;
                unsigned w = ((const unsigned*)&uk)[t >> 1];
                unsigned akv = (w >> ((t & 1) * 16)) & 0xffffu;
                int d0 = lane - j;             // <0 -> masked out
                unsigned v0 = bt[aqv0 ^ akv ^ (unsigned)apt[wid][d0 & 127]] & 1u;
                acc0 ^= (d0 >= 0) ? v0 : 0u;
                int d1 = lane + 64 - j;        // in [1,127]: always active
                unsigned v1 = bt[aqv1 ^ akv ^ (unsigned)apt[wid][d1]] & 1u;
                acc1 ^= v1;
            }
        }
        for (int s8 = 8; s8 < 16; ++s8) {      // j = 64..127: only upper query
            uint4 uk = *(const uint4*)&akT[wid][s8 * 8];
            #pragma unroll
            for (int t = 0; t < 8; ++t) {
                int j = s8 * 8 + t;
                unsigned w = ((const unsigned*)&uk)[t >> 1];
                unsigned akv = (w >> ((t & 1) * 16)) & 0xffffu;
                int d1 = lane + 64 - j;        // <0 -> masked out
                unsigned v1 = bt[aqv1 ^ akv ^ (unsigned)apt[wid][d1 & 127]] & 1u;
                acc1 ^= (d1 >= 0) ? v1 : 0u;
            }
        }
        rlo = __ballot(acc0 != 0u);
        rhi = __ballot(acc1 != 0u);
    }

    if (lane == 0) {
        parts[wid][0] = (unsigned)rlo;
        parts[wid][1] = (unsigned)(rlo >> 32);
        parts[wid][2] = (unsigned)rhi;
        parts[wid][3] = (unsigned)(rhi >> 32);
    }
    __syncthreads();   // barrier #2: parts visible

    // ---- per-group count (0..4) per query bit; fully overwrites slot ----
    if (tid < S) {
        int i = tid, tot = 0;
        #pragma unroll
        for (int hh = 0; hh < 4; ++hh)
            tot += (parts[hh][i >> 5] >> (i & 31)) & 1;
        pc[((size_t)g * 256 + n) * 128 + i] = (unsigned char)tot;
    }
}

__global__ __launch_bounds__(128) void vote_kernel(
    const unsigned char* __restrict__ pc,  // [4][256][128]
    int* __restrict__ out)                 // [S,B]
{
    const int n = blockIdx.x;              // 0..255
    const int i = threadIdx.x;             // 0..127
    int tot = pc[(size_t)(0 * 256 + n) * 128 + i]
            + pc[(size_t)(1 * 256 + n) * 128 + i]
            + pc[(size_t)(2 * 256 + n) * 128 + i]
            + pc[(size_t)(3 * 256 + n) * 128 + i];
    out[i * B + n] = (tot > (H / 2)) ? 1 : 0;
}

extern "C" void kernel_launch(void* const* d_in, const int* in_sizes, int n_in,
                              void* d_out, int out_size, void* d_ws, size_t ws_size,
                              hipStream_t stream) {
    const int*   tokens      = (const int*)d_in[0];
    const float* memory      = (const float*)d_in[1];
    const int*   connections = (const int*)d_in[2];
    int*         out         = (int*)d_out;
    unsigned char*      pc   = (unsigned char*)d_ws;                      // 128 KB @ 0
    unsigned*           tokP = (unsigned*)((char*)d_ws + (128u << 10));   // 4 KB @ 128K
    unsigned long long* psW  = (unsigned long long*)((char*)d_ws + (1u << 20));  // 2 MB @ 1M
    unsigned char*      psB  = (unsigned char*)d_ws + (4u << 20);         // 16 MB @ 4M
    (void)in_sizes; (void)n_in; (void)out_size; (void)ws_size;

    prep_kernel<<<1032, 256, 0, stream>>>(tokens, memory, connections, tokP, psW, psB);
    softram_kernel<<<4 * B, 256, 0, stream>>>(tokP, connections, psW, psB, pc);
    vote_kernel<<<B, 128, 0, stream>>>(pc, out);
}

// Round 7
// 108.341 us; speedup vs baseline: 1.0890x; 1.0890x over previous
//
#include <hip/hip_runtime.h>

// SoftRAM attention: S=128, B=256 bits, H=16 heads, NB=12 bits/neuron, PB=7.
// addr(i,j,h,n) = aq_i | ak_j | ap_{i-j}, disjoint bit groups per (h,n).
//
// R15 == R14 with the launch-size bug fixed: R14 launched 1024 blocks but
// the 2-rows-per-block split needs 4096/2 = 2048; heads 8..15 were never
// computed (absmax fail from uninitialized pres). Split-row math re-audited,
// no other defect found; grid corrected to 2048.
//
// Design (unchanged): occupancy doubling. Each (h,n) row is split across TWO
// waves (sub=0/1): 2048 blocks x 4 waves = 8192 waves = 32/CU ceiling,
// LDS ~14.9KB/block, __launch_bounds__(256,8) (VGPR target <=64).
//  - each wave: 8KB load half, half the sigma byte-table pack, half the
//    class build, 32 of 64 repack ballots (halves merged via LDS wsh),
//    own key/query half of the sweep; prefix carries (Abase/Cbase/fbu)
//    cross the pair via LDS barriers.
//  - results stored directly to pres[4096][2] u64; vote_kernel does the
//    16-head majority. All inner math verbatim from R11 (verified absmax 0).

#define S 128
#define B 256
#define H 16
#define NB 12

__device__ __forceinline__ unsigned sig(unsigned x) {
    return x ^ ((x >> 3) & 0x70u) ^ ((x >> 6) & 0x70u);
}

// token bit c lives at packed word TW(c), bit TP(c)
#define TW(c) ((((c) & 3) << 1) + ((c) >> 7))
#define TP(c) (((c) >> 2) & 31)

__global__ __launch_bounds__(256) void pack_kernel(
    const int* __restrict__ tokens,        // [S,B] 0/1
    unsigned* __restrict__ tokP)           // [8][S] packed
{
    const int wid  = threadIdx.x >> 6;
    const int lane = threadIdx.x & 63;
    const int4* tp = (const int4*)tokens;
    #pragma unroll
    for (int r = 0; r < 4; ++r) {
        int i = blockIdx.x * 16 + wid * 4 + r;
        int4 x = tp[i * 64 + lane];        // coalesced: full row of 256 ints
        unsigned long long B0 = __ballot((x.x & 1) != 0);  // bit l = tok[4l+0]
        unsigned long long B1 = __ballot((x.y & 1) != 0);
        unsigned long long B2 = __ballot((x.z & 1) != 0);
        unsigned long long B3 = __ballot((x.w & 1) != 0);
        int c = lane >> 1;                 // word index = comp*2 + half
        unsigned long long s01 = (c & 1) ? B1 : B0;
        unsigned long long s23 = (c & 1) ? B3 : B2;
        unsigned long long s   = (c & 2) ? s23 : s01;
        unsigned word = (lane & 1) ? (unsigned)(s >> 32) : (unsigned)s;
        if (lane < 8) tokP[lane * 128 + i] = word;
    }
}

__global__ __launch_bounds__(256, 8) void softram_kernel(
    const unsigned* __restrict__ tokP,     // [8][S] packed tokens
    const float* __restrict__ memory,      // [H,B,4096]
    const int* __restrict__ connections,   // [H,B,NB]
    unsigned long long* __restrict__ pres) // [4096][2] result bits per row
{
    const int tid  = threadIdx.x;
    const int wid  = tid >> 6;
    const int rs   = wid >> 1;             // row slot in block (0/1)
    const int sub  = wid & 1;              // half (0: lo, 1: hi)
    const int r    = blockIdx.x * 2 + rs;  // row = h*256+n
    const int lane = tid & 63;

    __shared__ __align__(16) unsigned char      bytetab[2][4096]; // 8 KB
    __shared__ __align__(16) unsigned int       tokT[8 * S];      // 4 KB
    __shared__ __align__(16) unsigned short     akT[2][S];        // key cls / sig(ak)
    __shared__ __align__(16) unsigned short     apt[2][S];        // sig(ap) (fb)
    __shared__ __align__(16) unsigned short     aqs[2][S];        // sig(aq) (fb)
    __shared__ __align__(16) unsigned long long wsh[2][64];       // 1 KB bit-LUT
    __shared__ unsigned long long baseS[2];                       // prefix carry
    __shared__ unsigned long long fbu[2];                         // fb upper part

    unsigned char* __restrict__ bt = bytetab[rs];

    // ---- own 8KB half-row, 4-deep register ring ----
    const float4* mp = (const float4*)(memory + ((size_t)r << 12));
    float4 va[4];
    #pragma unroll
    for (int t = 0; t < 4; ++t) va[t] = mp[lane + 64 * (sub * 8 + t)];

    // ---- conns in registers (wave-uniform scalars via shfl+readfirstlane) ----
    int c_l = (lane < NB) ? connections[(size_t)r * NB + lane] : 0;
    int cb[NB];
    #pragma unroll
    for (int b = 0; b < NB; ++b)
        cb[b] = __builtin_amdgcn_readfirstlane(__shfl(c_l, b));

    unsigned qmask = 0, kmask = 0, pmask = 0;
    #pragma unroll
    for (int b = 0; b < NB; ++b) {
        qmask |= (unsigned)(cb[b] < 256) << b;
        kmask |= (unsigned)(cb[b] >= 256 && cb[b] < 512) << b;
        pmask |= (unsigned)(cb[b] >= 512) << b;
    }
    const int qb = __popc(qmask);
    const int kb = __popc(kmask);
    const bool fast = (pmask == 0);

    // ---- stage packed tokens (4KB, coalesced, L2-hot) ----
    ((int4*)tokT)[tid] = ((const int4*)tokP)[tid];
    __syncthreads();   // BAR1: tokT visible

    // ---- phase1: class build, own half ii = sub*64+lane ----
    const int ii = sub * 64 + lane;
    unsigned qcls = 0;                     // fast: query class | fb: sig(aq)
    if (fast) {
        unsigned qc = 0, kc = 0;
        int qn = 0, kn = 0;
        #pragma unroll
        for (int b = 0; b < NB; ++b) {
            int c = cb[b];
            if (c < 256) {
                qc |= ((tokT[TW(c) * S + ii] >> TP(c)) & 1u) << qn;
                ++qn;
            } else {
                int c2 = c - 256;
                kc |= ((tokT[TW(c2) * S + ii] >> TP(c2)) & 1u) << kn;
                ++kn;
            }
        }
        akT[rs][ii] = (unsigned short)kc;
        qcls = qc;
    } else {
        unsigned aq = 0, ak = 0, ap = 0;
        #pragma unroll
        for (int b = 0; b < NB; ++b) {
            int c = cb[b];
            if (c < 256) {
                aq |= ((tokT[TW(c) * S + ii] >> TP(c)) & 1u) << b;
            } else if (c < 512) {
                int c2 = c - 256;
                ak |= ((tokT[TW(c2) * S + ii] >> TP(c2)) & 1u) << b;
            } else {
                ap |= (((unsigned)ii >> (c - 512)) & 1u) << b;
            }
        }
        akT[rs][ii] = (unsigned short)sig(ak);
        apt[rs][ii] = (unsigned short)sig(ap);
        aqs[rs][ii] = (unsigned short)sig(aq);
        qcls = sig(aq);
    }

    // ---- consume own tiles -> sigma byte-table half ----
    #pragma unroll
    for (int t = 0; t < 8; ++t) {
        float4 v = va[t & 3];
        if (t + 4 < 8) va[t & 3] = mp[lane + 64 * (sub * 8 + t + 4)];
        unsigned w = (unsigned)(v.x > 0.f)
                   | ((unsigned)(v.y > 0.f) << 8)
                   | ((unsigned)(v.z > 0.f) << 16)
                   | ((unsigned)(v.w > 0.f) << 24);
        *(unsigned*)&bt[sig(4u * (unsigned)(lane + 64 * (sub * 8 + t)))] = w;
    }
    __syncthreads();   // BAR2: bytetab + class tables complete

    unsigned long long rpart = 0;          // this wave's 64 result bits
    unsigned long long Wfull = 0;
    unsigned long long Vreg  = 0;          // formA sub1 carry
    unsigned Creg = 0;                     // formB sub1 carry
    unsigned acc_fb = 0;                   // fb sub1 carry

    if (fast) {
        // ---- phase2: repack own 32 words of the lane-distributed bit-LUT
        //      gbit = (Lcls << SBITS) | Scls; lane w holds bits [64w,64w+64)
        const bool formA = (qb <= 6);
        const int SBITS  = formA ? qb : kb;
        unsigned apl = 0, aul = 0;
        {
            int scnt = 0, lcnt = 0;
            #pragma unroll
            for (int b = 0; b < NB; ++b) {
                int c = cb[b];
                bool isS = formA ? (c < 256) : (c >= 256);
                if (isS) {
                    apl |= (((unsigned)lane >> scnt) & 1u) << b;
                    ++scnt;
                } else {
                    int p = SBITS + lcnt;
                    if (p < 6) apl |= (((unsigned)lane >> p) & 1u) << b;
                    else       aul |= (((unsigned)lane >> (p - 6)) & 1u) << b;
                    ++lcnt;
                }
            }
        }
        const unsigned spl  = sig(apl);
        const unsigned saul = sig(aul);
        unsigned Wlo = 0, Whi = 0;
        #pragma unroll 8
        for (int k = 0; k < 32; ++k) {
            int it = sub * 32 + k;
            unsigned sau  = (unsigned)__builtin_amdgcn_readlane((int)saul, it);
            unsigned bitv = bt[sau ^ spl] & 1u;   // sign at gbit = it*64+lane
            unsigned long long Bm = __ballot(bitv != 0u);
            Wlo = (lane == it) ? (unsigned)Bm : Wlo;
            Whi = (lane == it) ? (unsigned)(Bm >> 32) : Whi;
        }
        if ((lane >> 5) == sub)
            wsh[rs][lane] = ((unsigned long long)Whi << 32) | Wlo;
    } else {
        // ---- phase2: fb sweep own j-range (lanes = queries) ----
        if (sub == 0) {
            const unsigned aqv0 = qcls;                 // query i = lane
            const unsigned aqvU = aqs[rs][64 + lane];   // query i = 64+lane
            unsigned acc0 = 0, accP = 0;
            for (int s8 = 0; s8 < 8; ++s8) {            // j = 0..63
                uint4 uk = *(const uint4*)&akT[rs][s8 * 8];
                #pragma unroll
                for (int t = 0; t < 8; ++t) {
                    int j = s8 * 8 + t;
                    unsigned w = ((const unsigned*)&uk)[t >> 1];
                    unsigned akv = (w >> ((t & 1) * 16)) & 0xffffu;
                    int d0 = lane - j;                  // <0 -> masked out
                    unsigned v0 = bt[aqv0 ^ akv ^ (unsigned)apt[rs][d0 & 127]] & 1u;
                    acc0 ^= (d0 >= 0) ? v0 : 0u;
                    int d1 = lane + 64 - j;             // in [1,127]: active
                    unsigned v1 = bt[aqvU ^ akv ^ (unsigned)apt[rs][d1]] & 1u;
                    accP ^= v1;
                }
            }
            rpart = __ballot(acc0 != 0u);
            unsigned long long up = __ballot(accP != 0u);
            if (lane == 0) fbu[rs] = up;
        } else {
            const unsigned aqv1 = qcls;                 // query i = 64+lane
            unsigned acc1 = 0;
            for (int s8 = 8; s8 < 16; ++s8) {           // j = 64..127
                uint4 uk = *(const uint4*)&akT[rs][s8 * 8];
                #pragma unroll
                for (int t = 0; t < 8; ++t) {
                    int j = s8 * 8 + t;
                    unsigned w = ((const unsigned*)&uk)[t >> 1];
                    unsigned akv = (w >> ((t & 1) * 16)) & 0xffffu;
                    int d1 = lane + 64 - j;             // <0 -> masked out
                    unsigned v1 = bt[aqv1 ^ akv ^ (unsigned)apt[rs][d1 & 127]] & 1u;
                    acc1 ^= (d1 >= 0) ? v1 : 0u;
                }
            }
            acc_fb = acc1;
        }
    }
    __syncthreads();   // BAR3: wsh halves / fbu visible

    if (fast) {
        Wfull = wsh[rs][lane];             // full 64-word LUT, word per lane
        const bool formA = (qb <= 6);
        if (formA) {
            // prefix-XOR over own key half; lane j = key sub*64+j.
            unsigned kcls = akT[rs][ii];
            unsigned g0 = kcls << qb;
            unsigned long long V = __shfl(Wfull, (int)(g0 >> 6)) >> (g0 & 63u);
            #pragma unroll
            for (int d = 1; d < 64; d <<= 1) {
                unsigned long long u = __shfl_up(V, (unsigned)d);
                V ^= (lane >= d) ? u : 0ull;
            }
            if (sub == 0) {
                rpart = __ballot(((V >> qcls) & 1ull) != 0ull);
                unsigned long long Ab = __shfl(V, 63);
                if (lane == 0) baseS[rs] = Ab;
            } else {
                Vreg = V;                  // fold carry after BAR4
            }
        } else {
            // kb <= 5: one-hot key-class prefix parity word
            unsigned kcls = akT[rs][ii];
            unsigned C = 1u << kcls;
            #pragma unroll
            for (int d = 1; d < 64; d <<= 1) {
                unsigned u = __shfl_up(C, (unsigned)d);
                C ^= (lane >= d) ? u : 0u;
            }
            if (sub == 0) {
                unsigned g0a = qcls << kb;
                unsigned W0 = (unsigned)(__shfl(Wfull, (int)(g0a >> 6)) >> (g0a & 63u));
                rpart = __ballot((__popc(W0 & C) & 1) != 0);
                unsigned Cb = __shfl(C, 63);
                if (lane == 0) baseS[rs] = (unsigned long long)Cb;
            } else {
                Creg = C;
            }
        }
    } else if (sub == 1) {
        // fold A's always-active partial into the upper-query accumulators
        unsigned long long up = fbu[rs];
        acc_fb ^= (unsigned)((up >> lane) & 1ull);
        rpart = __ballot(acc_fb != 0u);
    }
    __syncthreads();   // BAR4: baseS visible

    if (fast && sub == 1) {
        const bool formA = (qb <= 6);
        if (formA) {
            unsigned long long V1 = Vreg ^ baseS[rs];
            rpart = __ballot(((V1 >> qcls) & 1ull) != 0ull);
        } else {
            unsigned C1 = Creg ^ (unsigned)baseS[rs];
            unsigned g0b = qcls << kb;
            unsigned W1 = (unsigned)(__shfl(Wfull, (int)(g0b >> 6)) >> (g0b & 63u));
            rpart = __ballot((__popc(W1 & C1) & 1) != 0);
        }
    }

    if (lane == 0) pres[(size_t)r * 2 + sub] = rpart;
}

__global__ __launch_bounds__(128) void vote_kernel(
    const unsigned long long* __restrict__ pres,  // [4096][2]
    int* __restrict__ out)                        // [S,B]
{
    const int n = blockIdx.x;              // 0..255
    const int i = threadIdx.x;             // 0..127
    const int w = i >> 6, b = i & 63;
    int tot = 0;
    #pragma unroll
    for (int h = 0; h < H; ++h)
        tot += (int)((pres[(size_t)(h * 256 + n) * 2 + w] >> b) & 1ull);
    out[i * B + n] = (tot > (H / 2)) ? 1 : 0;
}

extern "C" void kernel_launch(void* const* d_in, const int* in_sizes, int n_in,
                              void* d_out, int out_size, void* d_ws, size_t ws_size,
                              hipStream_t stream) {
    const int*   tokens      = (const int*)d_in[0];
    const float* memory      = (const float*)d_in[1];
    const int*   connections = (const int*)d_in[2];
    int*         out         = (int*)d_out;
    unsigned long long* pres = (unsigned long long*)d_ws;           // 64 KB @ 0
    unsigned*           tokP = (unsigned*)((char*)d_ws + (64u << 10)); // 4 KB @ 64K
    (void)in_sizes; (void)n_in; (void)out_size; (void)ws_size;

    pack_kernel<<<8, 256, 0, stream>>>(tokens, tokP);
    // 4096 rows, 2 rows/block -> 2048 blocks (R14 bug: launched 1024)
    softram_kernel<<<2048, 256, 0, stream>>>(tokP, memory, connections, pres);
    vote_kernel<<<B, 128, 0, stream>>>(pres, out);
}